// Round 4
// baseline (122.867 us; speedup 1.0000x reference)
//
#include <hip/hip_runtime.h>

#define NA 512
#define NB 128
#define OUTSTRIDE (3 * NA + 1)   // 1537 floats per batch row

__device__ __forceinline__ void accum(float f, float X, float Y, float Z,
                                      float cix, float ciy, float ciz,
                                      float* a, float& ep) {
    float d  = fmaf(f, 200.0f, -100.0f);
    float dx = cix - X;
    float dy = ciy - Y;
    float dz = ciz - Z;
    float r2 = fmaf(dx, dx, fmaf(dy, dy, dz * dz));
    float rinv = (r2 > 0.f) ? rsqrtf(r2) : 0.f;   // diagonal -> 0 (diff==0 there)
    float s = d * rinv;
    a[0] = fmaf(s, dx, a[0]);
    a[1] = fmaf(s, dy, a[1]);
    a[2] = fmaf(s, dz, a[2]);
    ep += s;
}

// Block = 256 threads = 4 waves; block handles batch b, 32 consecutive rows.
// Wave w owns 8 rows. Lane owns j-window {lane*4+q + p*256 : q<4, p<2} (8 j's,
// coords in registers). Every fe load: wave-contiguous 1 KB (perfect coalescing).
// Per-lane acc[8][3]; 3-step butterfly + LDS finish for the cross-lane reduce.
__global__ __launch_bounds__(256, 4) void eij_main(const float* __restrict__ fe,
                                                   const float* __restrict__ coords,
                                                   float* __restrict__ out,
                                                   float* __restrict__ ws) {
    const int b    = blockIdx.x >> 4;    // 16 row-groups per batch
    const int rg   = blockIdx.x & 15;
    const int w    = threadIdx.x >> 6;
    const int lane = threadIdx.x & 63;

    __shared__ __align__(16) float sc[3][NA];   // coords SoA
    __shared__ float sRed[4][8][25];            // [wave][lane-group][24 F + ep]

    // Stage coords[b] (512 x 3) into SoA LDS.
    const float* cb = coords + (size_t)b * (NA * 3);
    for (int t = threadIdx.x; t < NA * 3; t += 256) {
        int j = t / 3;
        int comp = t - 3 * j;
        sc[comp][j] = cb[t];
    }
    __syncthreads();

    // Preload this lane's 8 j-coords into registers (one-time LDS reads).
    float cjx[2][4], cjy[2][4], cjz[2][4];
    #pragma unroll
    for (int p = 0; p < 2; ++p) {
        const int j0 = p * 256 + lane * 4;
        #pragma unroll
        for (int q = 0; q < 4; ++q) {
            cjx[p][q] = sc[0][j0 + q];
            cjy[p][q] = sc[1][j0 + q];
            cjz[p][q] = sc[2][j0 + q];
        }
    }

    const int i0 = rg * 32 + w * 8;
    const float* base = fe + ((size_t)(b * NA + i0)) * NA;

    float acc[8][3];
    #pragma unroll
    for (int r = 0; r < 8; ++r) { acc[r][0] = 0.f; acc[r][1] = 0.f; acc[r][2] = 0.f; }
    float ep = 0.f;

    #pragma unroll
    for (int r = 0; r < 8; ++r) {
        const float* rowp = base + (size_t)r * NA + lane * 4;
        const float4 f0 = *(const float4*)(rowp);          // wave: 1 KB contiguous
        const float4 f1 = *(const float4*)(rowp + 256);    // wave: 1 KB contiguous
        const float cix = sc[0][i0 + r];   // broadcast (all lanes same addr)
        const float ciy = sc[1][i0 + r];
        const float ciz = sc[2][i0 + r];
        accum(f0.x, cjx[0][0], cjy[0][0], cjz[0][0], cix, ciy, ciz, acc[r], ep);
        accum(f0.y, cjx[0][1], cjy[0][1], cjz[0][1], cix, ciy, ciz, acc[r], ep);
        accum(f0.z, cjx[0][2], cjy[0][2], cjz[0][2], cix, ciy, ciz, acc[r], ep);
        accum(f0.w, cjx[0][3], cjy[0][3], cjz[0][3], cix, ciy, ciz, acc[r], ep);
        accum(f1.x, cjx[1][0], cjy[1][0], cjz[1][0], cix, ciy, ciz, acc[r], ep);
        accum(f1.y, cjx[1][1], cjy[1][1], cjz[1][1], cix, ciy, ciz, acc[r], ep);
        accum(f1.z, cjx[1][2], cjy[1][2], cjz[1][2], cix, ciy, ciz, acc[r], ep);
        accum(f1.w, cjx[1][3], cjy[1][3], cjz[1][3], cix, ciy, ciz, acc[r], ep);
    }

    // Butterfly over lane bits 3,4,5: lanes with equal (lane&7) end identical.
    #pragma unroll
    for (int off = 8; off <= 32; off <<= 1) {
        #pragma unroll
        for (int r = 0; r < 8; ++r) {
            acc[r][0] += __shfl_xor(acc[r][0], off);
            acc[r][1] += __shfl_xor(acc[r][1], off);
            acc[r][2] += __shfl_xor(acc[r][2], off);
        }
        ep += __shfl_xor(ep, off);
    }

    if (lane < 8) {
        #pragma unroll
        for (int r = 0; r < 8; ++r) {
            sRed[w][lane][r * 3 + 0] = acc[r][0];
            sRed[w][lane][r * 3 + 1] = acc[r][1];
            sRed[w][lane][r * 3 + 2] = acc[r][2];
        }
        sRed[w][lane][24] = ep;
    }
    __syncthreads();

    // Final block-level reduce: 96 threads handle (wave, row, comp); 1 thread E.
    const int t = threadIdx.x;
    if (t < 96) {
        const int w2 = t / 24;
        const int rc = t - w2 * 24;
        float s = 0.f;
        #pragma unroll
        for (int q = 0; q < 8; ++q) s += sRed[w2][q][rc];
        const int row = rg * 32 + w2 * 8 + rc / 3;
        out[(size_t)b * OUTSTRIDE + row * 3 + rc % 3] = s;
    } else if (t == 96) {
        float e = 0.f;
        #pragma unroll
        for (int w2 = 0; w2 < 4; ++w2)
            #pragma unroll
            for (int q = 0; q < 8; ++q) e += sRed[w2][q][24];
        ws[blockIdx.x] = e;
    }
}

// One tiny block: sum the 16 per-block partials per batch, write E.
__global__ void eij_finish(const float* __restrict__ ws, float* __restrict__ out) {
    int b = threadIdx.x;
    if (b < NB) {
        const float* p = ws + b * 16;
        float e = 0.f;
        #pragma unroll
        for (int k = 0; k < 16; ++k) e += p[k];
        out[(size_t)b * OUTSTRIDE + 3 * NA] = 0.5f * e;
    }
}

extern "C" void kernel_launch(void* const* d_in, const int* in_sizes, int n_in,
                              void* d_out, int out_size, void* d_ws, size_t ws_size,
                              hipStream_t stream) {
    const float* fe     = (const float*)d_in[0];
    const float* coords = (const float*)d_in[1];
    float* out          = (float*)d_out;
    float* ws           = (float*)d_ws;

    hipLaunchKernelGGL(eij_main, dim3(NB * 16), dim3(256), 0, stream, fe, coords, out, ws);
    hipLaunchKernelGGL(eij_finish, dim3(1), dim3(128), 0, stream, ws, out);
}

// Round 5
// 31.007 us; speedup vs baseline: 3.9625x; 3.9625x over previous
//
#include <hip/hip_runtime.h>

#define NA 512
#define NB 128
#define OUTSTRIDE (3 * NA + 1)   // 1537 floats per batch row

__device__ __forceinline__ void accum(float f, float X, float Y, float Z,
                                      float cix, float ciy, float ciz,
                                      float& fx, float& fy, float& fz, float& ep) {
    float d  = fmaf(f, 200.0f, -100.0f);
    float dx = cix - X;
    float dy = ciy - Y;
    float dz = ciz - Z;
    float r2 = fmaf(dx, dx, fmaf(dy, dy, dz * dz));
    float rinv = (r2 > 0.f) ? rsqrtf(r2) : 0.f;   // diagonal -> 0 (diff==0 there)
    float s = d * rinv;
    fx = fmaf(s, dx, fx);
    fy = fmaf(s, dy, fy);
    fz = fmaf(s, dz, fz);
    ep += s;
}

// Block = 256 threads = 4 waves; block handles batch b, 32 consecutive rows.
// Wave w owns 8 rows. lane: r = lane>>3 (row), c = lane&7 (position).
// Load t4: lane reads float4 at j = t4*32 + c*4  ->  8 lanes = 128 B contiguous
// per row (dense sectors), rows 2 KB apart. Coords: conflict-free broadcast
// b128 from LDS SoA. Reduction: 3-step butterfly over c only.
__global__ __launch_bounds__(256, 8) void eij_main(const float* __restrict__ fe,
                                                   const float* __restrict__ coords,
                                                   float* __restrict__ out,
                                                   float* __restrict__ ws) {
    const int b    = blockIdx.x >> 4;    // 16 row-groups per batch
    const int rg   = blockIdx.x & 15;
    const int w    = threadIdx.x >> 6;
    const int lane = threadIdx.x & 63;
    const int r    = lane >> 3;
    const int c    = lane & 7;

    __shared__ __align__(16) float s0[NA], s1[NA], s2[NA];  // coords SoA
    __shared__ float sE[4];

    // Stage coords[b] (512 x 3) into SoA LDS.
    const float* cb = coords + (size_t)b * (NA * 3);
    for (int t = threadIdx.x; t < NA * 3; t += 256) {
        int j = t / 3;
        int comp = t - 3 * j;
        float v = cb[t];
        if (comp == 0) s0[j] = v;
        else if (comp == 1) s1[j] = v;
        else s2[j] = v;
    }
    __syncthreads();

    const int i = rg * 32 + w * 8 + r;
    const float cix = s0[i], ciy = s1[i], ciz = s2[i];   // 8 addrs, 8-way broadcast

    const float4* rowp = (const float4*)(fe + ((size_t)(b * NA + i)) * NA) + c;

    float fx = 0.f, fy = 0.f, fz = 0.f, ep = 0.f;
    #pragma unroll
    for (int t4 = 0; t4 < 16; ++t4) {
        const float4 f = rowp[8 * t4];            // dense: 8 lanes = 128 B
        const int j0 = t4 * 32 + c * 4;
        const float4 X = *(const float4*)&s0[j0]; // banks c*4..c*4+3 -> all 32
        const float4 Y = *(const float4*)&s1[j0];
        const float4 Z = *(const float4*)&s2[j0];
        accum(f.x, X.x, Y.x, Z.x, cix, ciy, ciz, fx, fy, fz, ep);
        accum(f.y, X.y, Y.y, Z.y, cix, ciy, ciz, fx, fy, fz, ep);
        accum(f.z, X.z, Y.z, Z.z, cix, ciy, ciz, fx, fy, fz, ep);
        accum(f.w, X.w, Y.w, Z.w, cix, ciy, ciz, fx, fy, fz, ep);
    }

    // Reduce F over the 8 within-row positions (lane bits 0-2).
    #pragma unroll
    for (int off = 1; off <= 4; off <<= 1) {
        fx += __shfl_xor(fx, off);
        fy += __shfl_xor(fy, off);
        fz += __shfl_xor(fz, off);
        ep += __shfl_xor(ep, off);
    }

    if (c == 0) {
        float* ob = out + (size_t)b * OUTSTRIDE + (size_t)i * 3;
        ob[0] = fx;
        ob[1] = fy;
        ob[2] = fz;
    }

    // Finish E: reduce across rows (bits 3-5), then across waves via LDS.
    #pragma unroll
    for (int off = 8; off <= 32; off <<= 1)
        ep += __shfl_xor(ep, off);
    if (lane == 0) sE[w] = ep;
    __syncthreads();
    if (threadIdx.x == 0)
        ws[blockIdx.x] = sE[0] + sE[1] + sE[2] + sE[3];
}

// One tiny block: sum the 16 per-block partials per batch, write E.
__global__ void eij_finish(const float* __restrict__ ws, float* __restrict__ out) {
    int b = threadIdx.x;
    if (b < NB) {
        const float* p = ws + b * 16;
        float e = 0.f;
        #pragma unroll
        for (int k = 0; k < 16; ++k) e += p[k];
        out[(size_t)b * OUTSTRIDE + 3 * NA] = 0.5f * e;
    }
}

extern "C" void kernel_launch(void* const* d_in, const int* in_sizes, int n_in,
                              void* d_out, int out_size, void* d_ws, size_t ws_size,
                              hipStream_t stream) {
    const float* fe     = (const float*)d_in[0];
    const float* coords = (const float*)d_in[1];
    float* out          = (float*)d_out;
    float* ws           = (float*)d_ws;

    hipLaunchKernelGGL(eij_main, dim3(NB * 16), dim3(256), 0, stream, fe, coords, out, ws);
    hipLaunchKernelGGL(eij_finish, dim3(1), dim3(128), 0, stream, ws, out);
}